// Round 6
// baseline (329.922 us; speedup 1.0000x reference)
//
#include <hip/hip_runtime.h>
#include <hip/hip_cooperative_groups.h>

namespace cg = cooperative_groups;

typedef unsigned int u32;
typedef unsigned short u16;
typedef short s8v __attribute__((ext_vector_type(8)));     // 8 bf16 = 4 VGPR
typedef float f16v __attribute__((ext_vector_type(16)));   // 32x32 accumulator
typedef _Float16 h8 __attribute__((ext_vector_type(8)));   // 8 fp16 = 16 B

#define NB 4
#define NC 128
#define HW 12288
#define NS 1024

// resp = exp(20*(0.5*corr + 0.5 - 0.9995)) = exp(10*corr - 9.99)
#define EXP_A 10.0f
#define EXP_B (-9.99f)
#define ESCALE 4096.0f    // power of 2: e*ESCALE exact in fp32, cancels in e/sum

#define TSR 128           // s-rows per block (row-tile)
#define TP 256            // px per block
#define NPT (HW/TP)       // 48
#define NRT ((NB*NS)/TSR) // 32 row-tiles total (8 per batch)

__device__ inline u16 f2bf(float f) {            // RNE fp32->bf16
    u32 u = __float_as_uint(f);
    return (u16)((u + 0x7fffu + ((u >> 16) & 1u)) >> 16);
}
__device__ inline float bf2f(u16 h) { return __uint_as_float(((u32)h) << 16); }

__device__ inline void gload_lds16(const void* g, void* l) {
    __builtin_amdgcn_global_load_lds(
        (const __attribute__((address_space(1))) void*)g,
        (__attribute__((address_space(3))) void*)l, 16, 0, 0);
}

// ---------------------------------------------------------------------------
// prep (fused): blocks [0,768) transform tgt -> Bq hi/lo (bank-swizzled);
// blocks [768,2816) gather sampled vectors -> As hi/lo and zero sums.
// ---------------------------------------------------------------------------
__global__ __launch_bounds__(256) void prep(
    const float* __restrict__ src, const float* __restrict__ tgt,
    const int* __restrict__ loc,
    u16* __restrict__ ahi, u16* __restrict__ alo,
    u16* __restrict__ bhi, u16* __restrict__ blo,
    float* __restrict__ sums)
{
    int blk = blockIdx.x, t = threadIdx.x;
    if (blk < (HW / 64) * NB) {
        int b = blk / (HW / 64), pt = blk - b * (HW / 64);
        int pxl = t & 63, u = t >> 6;
        int px = pt * 64 + pxl;
        int slot = u ^ ((px >> 1) & 3);
#pragma unroll
        for (int kc = 0; kc < 4; ++kc) {
            int c0 = kc * 32 + u * 8;
            u32 hq[4], lq[4];
#pragma unroll
            for (int k = 0; k < 4; ++k) {
                float v0 = tgt[((size_t)(b * NC + c0 + 2 * k)) * HW + px];
                float v1 = tgt[((size_t)(b * NC + c0 + 2 * k + 1)) * HW + px];
                u16 h0 = f2bf(v0), h1 = f2bf(v1);
                u16 l0 = f2bf(v0 - bf2f(h0)), l1 = f2bf(v1 - bf2f(h1));
                hq[k] = (u32)h0 | ((u32)h1 << 16);
                lq[k] = (u32)l0 | ((u32)l1 << 16);
            }
            size_t off = (((size_t)((b * 4 + kc) * HW + px)) * 4 + slot) * 8;  // u16 units
            *(uint4*)(bhi + off) = make_uint4(hq[0], hq[1], hq[2], hq[3]);
            *(uint4*)(blo + off) = make_uint4(lq[0], lq[1], lq[2], lq[3]);
        }
    } else {
        int sb = blk - (HW / 64) * NB;
        int gid = sb * 256 + t;
        if (gid < NB * NS) sums[gid] = 0.0f;
        int bs = sb * 2 + (t >> 7);
        int c  = t & 127;
        int b  = bs >> 10, s = bs & 1023;
        int l  = loc[bs];
        float v = src[((size_t)(b * NC + c)) * HW + l];
        u16 h  = f2bf(v);
        u16 lo = f2bf(v - bf2f(h));
        int kc = c >> 5, u = (c >> 3) & 3, e = c & 7;
        int slot = u ^ ((s >> 1) & 3);
        size_t off = ((size_t)((b * 4 + kc) * NS + s)) * 32 + slot * 8 + e;
        ahi[off] = h;
        alo[off] = lo;
    }
}

// ---------------------------------------------------------------------------
// corr_norm (cooperative, grid 512 x 256, 2 blocks/CU): phase 1 runs the
// verified round-5 GEMM body on 3 tiles per block (same rt -> A L2-hot;
// XCD-chunked pt), storing fp16 e and accumulating row sums; then
// __threadfence + grid.sync; phase 2 normalizes 8 rows per block while
// ebuf is still L3-resident. Removes the rescale dispatch + its launch
// dependency stall. Numerics identical to the fallback path.
// ---------------------------------------------------------------------------
__global__ __launch_bounds__(256, 2) void corr_norm(
    const u16* __restrict__ bhi, const u16* __restrict__ blo,
    const u16* __restrict__ ahi, const u16* __restrict__ alo,
    const float* __restrict__ mask, float* __restrict__ sums,
    _Float16* __restrict__ ebuf, float* __restrict__ out)
{
    __shared__ __align__(1024) char sm[49152];  // Ah 8K | Al 8K | Bh 16K | Bl 16K

    int blk = blockIdx.x;                  // 0..511
    int xcd = blk & 7, idx = blk >> 3;     // idx: 0..63
    int rt  = idx & 31;                    // row-tile, SAME for all 3 sub-tiles
    int b   = rt >> 3, st2 = rt & 7;

    int t = threadIdx.x, w = t >> 6, l = t & 63, ln = l & 31, h = l >> 5;
    int ws = w >> 1, wp = w & 1;

    // ---- phase 1: three 128x256 tiles
    for (int k = 0; k < 3; ++k) {
        int tid = idx + (k << 6);          // 0..191 within this XCD
        int pt  = xcd * 6 + (tid >> 5);    // 6 pt-panels per XCD

        f16v acc[2][4];
#pragma unroll
        for (int i = 0; i < 2; ++i)
#pragma unroll
            for (int j = 0; j < 4; ++j)
#pragma unroll
                for (int r2 = 0; r2 < 16; ++r2) acc[i][j][r2] = 0.0f;

        for (int kc = 0; kc < 4; ++kc) {
            const char* ga_h = (const char*)ahi + ((size_t)((b * 4 + kc) * NS + st2 * TSR)) * 64;
            const char* ga_l = (const char*)alo + ((size_t)((b * 4 + kc) * NS + st2 * TSR)) * 64;
            const char* gb_h = (const char*)bhi + ((size_t)((b * 4 + kc) * HW + pt * TP)) * 64;
            const char* gb_l = (const char*)blo + ((size_t)((b * 4 + kc) * HW + pt * TP)) * 64;
#pragma unroll
            for (int it = 0; it < 12; ++it) {
                int q = w * 12 + it;               // wave-uniform, 0..47
                const char* g; int inner;
                if (q < 8)       { g = ga_h; inner = q; }
                else if (q < 16) { g = ga_l; inner = q - 8; }
                else if (q < 32) { g = gb_h; inner = q - 16; }
                else             { g = gb_l; inner = q - 32; }
                gload_lds16(g + inner * 1024 + l * 16, sm + q * 1024);
            }
            __syncthreads();

#pragma unroll
            for (int kk2 = 0; kk2 < 2; ++kk2) {
                int u = kk2 * 2 + h;
                s8v a_h[2], a_l[2], b_h[4], b_l[4];
#pragma unroll
                for (int i = 0; i < 2; ++i) {
                    int row = ws * 64 + i * 32 + ln;
                    int sl = u ^ ((row >> 1) & 3);
                    a_h[i] = *(const s8v*)(sm + 0 * 8192 + row * 64 + sl * 16);
                    a_l[i] = *(const s8v*)(sm + 1 * 8192 + row * 64 + sl * 16);
                }
#pragma unroll
                for (int j = 0; j < 4; ++j) {
                    int px = wp * 128 + j * 32 + ln;
                    int sl = u ^ ((px >> 1) & 3);
                    b_h[j] = *(const s8v*)(sm + 16384 + px * 64 + sl * 16);
                    b_l[j] = *(const s8v*)(sm + 32768 + px * 64 + sl * 16);
                }
                __builtin_amdgcn_s_setprio(1);
#pragma unroll
                for (int i = 0; i < 2; ++i)
#pragma unroll
                    for (int j = 0; j < 4; ++j) {
                        acc[i][j] = __builtin_amdgcn_mfma_f32_32x32x16_bf16(a_h[i], b_h[j], acc[i][j], 0, 0, 0);
                        acc[i][j] = __builtin_amdgcn_mfma_f32_32x32x16_bf16(a_l[i], b_h[j], acc[i][j], 0, 0, 0);
                        acc[i][j] = __builtin_amdgcn_mfma_f32_32x32x16_bf16(a_h[i], b_l[j], acc[i][j], 0, 0, 0);
                    }
                __builtin_amdgcn_s_setprio(0);
            }
            __syncthreads();
        }

        // epilogue for this tile
        float mvs[4];
#pragma unroll
        for (int j = 0; j < 4; ++j)
            mvs[j] = mask[(size_t)b * HW + pt * TP + wp * 128 + j * 32 + ln] * ESCALE;

        float* rs = (float*)sm;     // 32 KB of the 48 KB buffer (chunk loop done)
        size_t base = ((size_t)(b * NS + st2 * TSR)) * HW + pt * TP + wp * 128 + ln;
        _Float16* eb0 = ebuf + base;
#pragma unroll
        for (int i = 0; i < 2; ++i) {
            int rb = ws * 64 + i * 32 + 4 * h;
#pragma unroll
            for (int r2 = 0; r2 < 16; ++r2) {
                int row = rb + (r2 & 3) + 8 * (r2 >> 2);    // 0..127
                float tot = 0.0f;
#pragma unroll
                for (int j = 0; j < 4; ++j) {
                    float e = __expf(fmaf(acc[i][j][r2], EXP_A, EXP_B)) * mvs[j];
                    eb0[(size_t)row * HW + j * 32] = (_Float16)e;
                    tot += e;
                }
                rs[(wp * TSR + row) * 32 + ln] = tot;
            }
        }
        __syncthreads();
        int row2 = t & 127, half = t >> 7;
        float tot = 0.0f;
#pragma unroll
        for (int c = 0; c < 32; ++c)
            tot += rs[(half * TSR + row2) * 32 + ((c + t) & 31)];
        atomicAdd(&sums[b * NS + st2 * TSR + row2], tot);
        __syncthreads();   // rs reads done before next tile's stage overwrites sm
    }

    // ---- grid-wide sync: all e-stores + sum-atomics visible
    __threadfence();
    cg::this_grid().sync();

    // ---- phase 2: normalize 8 rows per block (ebuf still L3-resident)
    int base_row = blk * 8;
#pragma unroll
    for (int k = 0; k < 8; ++k) {
        int row = base_row + k;
        float sv = __hip_atomic_load(&sums[row], __ATOMIC_RELAXED, __HIP_MEMORY_SCOPE_AGENT);
        float inv = 1.0f / sv;
        const h8* p = (const h8*)(ebuf + (size_t)row * HW);
        float4* o = (float4*)(out + (size_t)row * HW);
#pragma unroll
        for (int i = 0; i < 6; ++i) {
            int idx2 = t + i * 256;
            h8 v = p[idx2];
            float4 a, c;
            a.x = (float)v[0] * inv; a.y = (float)v[1] * inv;
            a.z = (float)v[2] * inv; a.w = (float)v[3] * inv;
            c.x = (float)v[4] * inv; c.y = (float)v[5] * inv;
            c.z = (float)v[6] * inv; c.w = (float)v[7] * inv;
            o[2 * idx2]     = a;
            o[2 * idx2 + 1] = c;
        }
    }
}

// ---------------------------------------------------------------------------
// Fallback path (round-5 verified): corr_fused<F16> + rescale16/rescale32.
// ---------------------------------------------------------------------------
template <int F16>
__global__ __launch_bounds__(256, 2) void corr_fused(
    const u16* __restrict__ bhi, const u16* __restrict__ blo,
    const u16* __restrict__ ahi, const u16* __restrict__ alo,
    const float* __restrict__ mask, float* __restrict__ sums,
    _Float16* __restrict__ ebuf, float* __restrict__ out)
{
    __shared__ __align__(1024) char sm[49152];

    int f = blockIdx.x;
    int xcd = f & 7, r = f >> 3;
    int pt = xcd * 6 + (r >> 5);
    int rt = r & 31;
    int b  = rt >> 3, st2 = rt & 7;

    int t = threadIdx.x, w = t >> 6, l = t & 63, ln = l & 31, h = l >> 5;
    int ws = w >> 1, wp = w & 1;

    f16v acc[2][4];
#pragma unroll
    for (int i = 0; i < 2; ++i)
#pragma unroll
        for (int j = 0; j < 4; ++j)
#pragma unroll
            for (int r2 = 0; r2 < 16; ++r2) acc[i][j][r2] = 0.0f;

    for (int kc = 0; kc < 4; ++kc) {
        const char* ga_h = (const char*)ahi + ((size_t)((b * 4 + kc) * NS + st2 * TSR)) * 64;
        const char* ga_l = (const char*)alo + ((size_t)((b * 4 + kc) * NS + st2 * TSR)) * 64;
        const char* gb_h = (const char*)bhi + ((size_t)((b * 4 + kc) * HW + pt * TP)) * 64;
        const char* gb_l = (const char*)blo + ((size_t)((b * 4 + kc) * HW + pt * TP)) * 64;
#pragma unroll
        for (int it = 0; it < 12; ++it) {
            int q = w * 12 + it;
            const char* g; int inner;
            if (q < 8)       { g = ga_h; inner = q; }
            else if (q < 16) { g = ga_l; inner = q - 8; }
            else if (q < 32) { g = gb_h; inner = q - 16; }
            else             { g = gb_l; inner = q - 32; }
            gload_lds16(g + inner * 1024 + l * 16, sm + q * 1024);
        }
        __syncthreads();

#pragma unroll
        for (int kk2 = 0; kk2 < 2; ++kk2) {
            int u = kk2 * 2 + h;
            s8v a_h[2], a_l[2], b_h[4], b_l[4];
#pragma unroll
            for (int i = 0; i < 2; ++i) {
                int row = ws * 64 + i * 32 + ln;
                int sl = u ^ ((row >> 1) & 3);
                a_h[i] = *(const s8v*)(sm + 0 * 8192 + row * 64 + sl * 16);
                a_l[i] = *(const s8v*)(sm + 1 * 8192 + row * 64 + sl * 16);
            }
#pragma unroll
            for (int j = 0; j < 4; ++j) {
                int px = wp * 128 + j * 32 + ln;
                int sl = u ^ ((px >> 1) & 3);
                b_h[j] = *(const s8v*)(sm + 16384 + px * 64 + sl * 16);
                b_l[j] = *(const s8v*)(sm + 32768 + px * 64 + sl * 16);
            }
            __builtin_amdgcn_s_setprio(1);
#pragma unroll
            for (int i = 0; i < 2; ++i)
#pragma unroll
                for (int j = 0; j < 4; ++j) {
                    acc[i][j] = __builtin_amdgcn_mfma_f32_32x32x16_bf16(a_h[i], b_h[j], acc[i][j], 0, 0, 0);
                    acc[i][j] = __builtin_amdgcn_mfma_f32_32x32x16_bf16(a_l[i], b_h[j], acc[i][j], 0, 0, 0);
                    acc[i][j] = __builtin_amdgcn_mfma_f32_32x32x16_bf16(a_h[i], b_l[j], acc[i][j], 0, 0, 0);
                }
            __builtin_amdgcn_s_setprio(0);
        }
        __syncthreads();
    }

    float mvs[4];
#pragma unroll
    for (int j = 0; j < 4; ++j)
        mvs[j] = mask[(size_t)b * HW + pt * TP + wp * 128 + j * 32 + ln] * ESCALE;

    float* rs = (float*)sm;
    size_t base = ((size_t)(b * NS + st2 * TSR)) * HW + pt * TP + wp * 128 + ln;
    _Float16* eb0 = ebuf + base;
    float*    ob0 = out  + base;
#pragma unroll
    for (int i = 0; i < 2; ++i) {
        int rb = ws * 64 + i * 32 + 4 * h;
#pragma unroll
        for (int r2 = 0; r2 < 16; ++r2) {
            int row = rb + (r2 & 3) + 8 * (r2 >> 2);
            float tot = 0.0f;
#pragma unroll
            for (int j = 0; j < 4; ++j) {
                float e = __expf(fmaf(acc[i][j][r2], EXP_A, EXP_B)) * mvs[j];
                if (F16) eb0[(size_t)row * HW + j * 32] = (_Float16)e;
                else     ob0[(size_t)row * HW + j * 32] = e;
                tot += e;
            }
            rs[(wp * TSR + row) * 32 + ln] = tot;
        }
    }
    __syncthreads();
    int row2 = t & 127, half = t >> 7;
    float tot = 0.0f;
#pragma unroll
    for (int c = 0; c < 32; ++c)
        tot += rs[(half * TSR + row2) * 32 + ((c + t) & 31)];
    atomicAdd(&sums[b * NS + st2 * TSR + row2], tot);
}

__global__ __launch_bounds__(256) void rescale16(
    const float* __restrict__ sums, const _Float16* __restrict__ ebuf,
    float* __restrict__ out)
{
    int bs = blockIdx.x;
    float inv = 1.0f / sums[bs];
    const h8* p = (const h8*)(ebuf + (size_t)bs * HW);
    float4* o = (float4*)(out + (size_t)bs * HW);
    int t = threadIdx.x;
#pragma unroll
    for (int i = 0; i < 6; ++i) {
        int idx = t + i * 256;
        h8 v = p[idx];
        float4 a, c;
        a.x = (float)v[0] * inv; a.y = (float)v[1] * inv;
        a.z = (float)v[2] * inv; a.w = (float)v[3] * inv;
        c.x = (float)v[4] * inv; c.y = (float)v[5] * inv;
        c.z = (float)v[6] * inv; c.w = (float)v[7] * inv;
        o[2 * idx]     = a;
        o[2 * idx + 1] = c;
    }
}

__global__ __launch_bounds__(256) void rescale32(
    const float* __restrict__ sums, float* __restrict__ out)
{
    int bs = blockIdx.x;
    float inv = 1.0f / sums[bs];
    float4* p = (float4*)(out + (size_t)bs * HW);
    int t = threadIdx.x;
#pragma unroll
    for (int i = 0; i < 12; ++i) {
        float4 v = p[t + i * 256];
        v.x *= inv; v.y *= inv; v.z *= inv; v.w *= inv;
        p[t + i * 256] = v;
    }
}

extern "C" void kernel_launch(void* const* d_in, const int* in_sizes, int n_in,
                              void* d_out, int out_size, void* d_ws, size_t ws_size,
                              hipStream_t stream) {
    const float* src  = (const float*)d_in[0];
    const float* tgt  = (const float*)d_in[1];
    const int*   loc  = (const int*)d_in[2];
    const float* mask = (const float*)d_in[3];
    float* out = (float*)d_out;

    char* ws = (char*)d_ws;
    const size_t BPLANE = (size_t)NB * 4 * HW * 32 * sizeof(u16);  // 12.58 MB
    const size_t APLANE = (size_t)NB * 4 * NS * 32 * sizeof(u16);  //  1.05 MB
    const size_t EPLANE = (size_t)NB * NS * HW * sizeof(_Float16); // 100.7 MB
    u16* bhi = (u16*)ws;
    u16* blo = (u16*)(ws + BPLANE);
    u16* ahi = (u16*)(ws + 2 * BPLANE);
    u16* alo = (u16*)(ws + 2 * BPLANE + APLANE);
    float* sums = (float*)(ws + 2 * BPLANE + 2 * APLANE);          // 16 KB used
    _Float16* ebuf = (_Float16*)(ws + 2 * BPLANE + 2 * APLANE + 65536);
    const size_t NEED = 2 * BPLANE + 2 * APLANE + 65536 + EPLANE;  // ~128 MB

    prep<<<dim3((HW / 64) * NB + NB * NS / 2), 256, 0, stream>>>(
        src, tgt, loc, ahi, alo, bhi, blo, sums);

    bool coop_done = false;
    if (ws_size >= NEED) {
        static int coop_state = -1;   // -1 unknown, 1 usable, 0 not
        if (coop_state < 0) {
            int nb = 0, ncu = 0, dev = 0;
            hipGetDevice(&dev);
            hipError_t e1 = hipOccupancyMaxActiveBlocksPerMultiprocessor(
                &nb, (const void*)corr_norm, 256, 0);
            hipError_t e2 = hipDeviceGetAttribute(
                &ncu, hipDeviceAttributeMultiprocessorCount, dev);
            coop_state = (e1 == hipSuccess && e2 == hipSuccess &&
                          nb >= 2 && nb * ncu >= 512) ? 1 : 0;
        }
        if (coop_state == 1) {
            void* kargs[] = {(void*)&bhi, (void*)&blo, (void*)&ahi, (void*)&alo,
                             (void*)&mask, (void*)&sums, (void*)&ebuf, (void*)&out};
            coop_done = (hipLaunchCooperativeKernel((const void*)corr_norm,
                          dim3(512), dim3(256), kargs, 0, stream) == hipSuccess);
        }
    }

    if (!coop_done) {
        dim3 g(NPT * NRT);   // 1536 flat, XCD-chunked decode in-kernel
        if (ws_size >= NEED) {
            corr_fused<1><<<g, 256, 0, stream>>>(bhi, blo, ahi, alo, mask, sums, ebuf, out);
            rescale16<<<dim3(NB * NS), 256, 0, stream>>>(sums, ebuf, out);
        } else {
            corr_fused<0><<<g, 256, 0, stream>>>(bhi, blo, ahi, alo, mask, sums, ebuf, out);
            rescale32<<<dim3(NB * NS), 256, 0, stream>>>(sums, out);
        }
    }
}

// Round 7
// 326.604 us; speedup vs baseline: 1.0102x; 1.0102x over previous
//
#include <hip/hip_runtime.h>

typedef unsigned int u32;
typedef unsigned short u16;
typedef short s8v __attribute__((ext_vector_type(8)));     // 8 bf16 = 4 VGPR
typedef float f16v __attribute__((ext_vector_type(16)));   // 32x32 accumulator
typedef _Float16 h8 __attribute__((ext_vector_type(8)));   // 8 fp16 = 16 B

#define NB 4
#define NC 128
#define HW 12288
#define NS 1024

// resp = exp(20*(0.5*corr + 0.5 - 0.9995)) = exp(10*corr - 9.99)
#define EXP_A 10.0f
#define EXP_B (-9.99f)
#define ESCALE 4096.0f    // power of 2: e*ESCALE exact in fp32, cancels in e/sum

#define TS 256            // s-tile per block
#define TP 256            // px-tile per block
#define NPT (HW/TP)       // 48
#define NST ((NB*NS)/TS)  // 16 row-tiles total (4 per batch)

__device__ inline u16 f2bf(float f) {            // RNE fp32->bf16
    u32 u = __float_as_uint(f);
    return (u16)((u + 0x7fffu + ((u >> 16) & 1u)) >> 16);
}
__device__ inline float bf2f(u16 h) { return __uint_as_float(((u32)h) << 16); }

__device__ inline void gload_lds16(const void* g, void* l) {
    __builtin_amdgcn_global_load_lds(
        (const __attribute__((address_space(1))) void*)g,
        (__attribute__((address_space(3))) void*)l, 16, 0, 0);
}

// ---------------------------------------------------------------------------
// prep (fused): blocks [0,768) transform tgt -> Bq hi/lo (bank-swizzled);
// blocks [768,2816) gather sampled vectors -> As hi/lo and zero sums.
// ---------------------------------------------------------------------------
__global__ __launch_bounds__(256) void prep(
    const float* __restrict__ src, const float* __restrict__ tgt,
    const int* __restrict__ loc,
    u16* __restrict__ ahi, u16* __restrict__ alo,
    u16* __restrict__ bhi, u16* __restrict__ blo,
    float* __restrict__ sums)
{
    int blk = blockIdx.x, t = threadIdx.x;
    if (blk < (HW / 64) * NB) {
        int b = blk / (HW / 64), pt = blk - b * (HW / 64);
        int pxl = t & 63, u = t >> 6;
        int px = pt * 64 + pxl;
        int slot = u ^ ((px >> 1) & 3);
#pragma unroll
        for (int kc = 0; kc < 4; ++kc) {
            int c0 = kc * 32 + u * 8;
            u32 hq[4], lq[4];
#pragma unroll
            for (int k = 0; k < 4; ++k) {
                float v0 = tgt[((size_t)(b * NC + c0 + 2 * k)) * HW + px];
                float v1 = tgt[((size_t)(b * NC + c0 + 2 * k + 1)) * HW + px];
                u16 h0 = f2bf(v0), h1 = f2bf(v1);
                u16 l0 = f2bf(v0 - bf2f(h0)), l1 = f2bf(v1 - bf2f(h1));
                hq[k] = (u32)h0 | ((u32)h1 << 16);
                lq[k] = (u32)l0 | ((u32)l1 << 16);
            }
            size_t off = (((size_t)((b * 4 + kc) * HW + px)) * 4 + slot) * 8;  // u16 units
            *(uint4*)(bhi + off) = make_uint4(hq[0], hq[1], hq[2], hq[3]);
            *(uint4*)(blo + off) = make_uint4(lq[0], lq[1], lq[2], lq[3]);
        }
    } else {
        int sb = blk - (HW / 64) * NB;
        int gid = sb * 256 + t;
        if (gid < NB * NS) sums[gid] = 0.0f;
        int bs = sb * 2 + (t >> 7);
        int c  = t & 127;
        int b  = bs >> 10, s = bs & 1023;
        int l  = loc[bs];
        float v = src[((size_t)(b * NC + c)) * HW + l];
        u16 h  = f2bf(v);
        u16 lo = f2bf(v - bf2f(h));
        int kc = c >> 5, u = (c >> 3) & 3, e = c & 7;
        int slot = u ^ ((s >> 1) & 3);
        size_t off = ((size_t)((b * 4 + kc) * NS + s)) * 32 + slot * 8 + e;
        ahi[off] = h;
        alo[off] = lo;
    }
}

// ---------------------------------------------------------------------------
// corr_fused<F16>: split-bf16 MFMA GEMM, 256s x 256px tile, 8 waves,
// 512 threads, DOUBLE-BUFFERED LDS (2 x 64 KB = 128 KB, 1 block/CU).
// Safe pipeline: STAGE(kc+1) into buf^1 is issued BEFORE computing buf, and
// only plain __syncthreads() separates phases. The barrier's vmcnt(0) drain
// now waits on loads that had the whole compute phase to land (stall ~=
// max(0, stage_lat - compute)), vs. the old serial full-latency stall.
// XCD-chunked decode: each XCD's resident blocks share (pt,b) B-panels
// (~3 MB, L2-fit) so the staged loads are mostly L2 hits.
// Stores unnormalized e (x ESCALE) and accumulates per-row sums.
// ---------------------------------------------------------------------------
template <int F16>
__global__ __launch_bounds__(512) void corr_fused(
    const u16* __restrict__ bhi, const u16* __restrict__ blo,
    const u16* __restrict__ ahi, const u16* __restrict__ alo,
    const float* __restrict__ mask, float* __restrict__ sums,
    _Float16* __restrict__ ebuf, float* __restrict__ out)
{
    __shared__ __align__(1024) char sm[131072];  // 2 x [Ah 16K|Al 16K|Bh 16K|Bl 16K]

    // XCD-chunked bijective decode: f in [0,768)
    int f = blockIdx.x;
    int xcd = f & 7, r = f >> 3;           // r: 0..95
    int pt  = xcd * 6 + (r >> 4);          // 0..47 (6 pt-panels per XCD)
    int rt  = r & 15;                      // row-tile 0..15
    int b   = rt >> 2, st = rt & 3;        // 4 row-tiles per batch

    int t = threadIdx.x, w = t >> 6, l = t & 63, ln = l & 31, h = l >> 5;
    int ws = w >> 1, wp = w & 1;

    f16v acc[2][4];
#pragma unroll
    for (int i = 0; i < 2; ++i)
#pragma unroll
        for (int j = 0; j < 4; ++j)
#pragma unroll
            for (int r2 = 0; r2 < 16; ++r2) acc[i][j][r2] = 0.0f;

    // Stage one 64 KB K-chunk into buf: 4 x 16 KB regions, 8 x 1 KB per wave.
    auto STAGE = [&](int kc, int buf) {
        const char* ga_h = (const char*)ahi + ((size_t)((b * 4 + kc) * NS + st * TS)) * 64;
        const char* ga_l = (const char*)alo + ((size_t)((b * 4 + kc) * NS + st * TS)) * 64;
        const char* gb_h = (const char*)bhi + ((size_t)((b * 4 + kc) * HW + pt * TP)) * 64;
        const char* gb_l = (const char*)blo + ((size_t)((b * 4 + kc) * HW + pt * TP)) * 64;
        char* dst = sm + buf * 65536;
#pragma unroll
        for (int it = 0; it < 8; ++it) {
            int q = w * 8 + it;                // wave-uniform, 0..63
            int rg = q >> 4, inner = q & 15;
            const char* g = rg == 0 ? ga_h : rg == 1 ? ga_l : rg == 2 ? gb_h : gb_l;
            gload_lds16(g + inner * 1024 + l * 16, dst + q * 1024);
        }
    };

    STAGE(0, 0);
    __syncthreads();                      // buf0 staged (prologue drain)

    for (int kc = 0; kc < 4; ++kc) {
        if (kc < 3) STAGE(kc + 1, (kc + 1) & 1);   // prefetch next chunk

        const char* base = sm + (kc & 1) * 65536;
#pragma unroll
        for (int kk2 = 0; kk2 < 2; ++kk2) {
            int u = kk2 * 2 + h;               // 16B unit within 32-k chunk
            s8v a_h[2], a_l[2], b_h[4], b_l[4];
#pragma unroll
            for (int i = 0; i < 2; ++i) {
                int row = ws * 64 + i * 32 + ln;
                int sl = u ^ ((row >> 1) & 3);
                a_h[i] = *(const s8v*)(base + 0 * 16384 + row * 64 + sl * 16);
                a_l[i] = *(const s8v*)(base + 1 * 16384 + row * 64 + sl * 16);
            }
#pragma unroll
            for (int j = 0; j < 4; ++j) {
                int px = wp * 128 + j * 32 + ln;
                int sl = u ^ ((px >> 1) & 3);
                b_h[j] = *(const s8v*)(base + 2 * 16384 + px * 64 + sl * 16);
                b_l[j] = *(const s8v*)(base + 3 * 16384 + px * 64 + sl * 16);
            }
            __builtin_amdgcn_s_setprio(1);
#pragma unroll
            for (int i = 0; i < 2; ++i)
#pragma unroll
                for (int j = 0; j < 4; ++j) {
                    acc[i][j] = __builtin_amdgcn_mfma_f32_32x32x16_bf16(a_h[i], b_h[j], acc[i][j], 0, 0, 0);
                    acc[i][j] = __builtin_amdgcn_mfma_f32_32x32x16_bf16(a_l[i], b_h[j], acc[i][j], 0, 0, 0);
                    acc[i][j] = __builtin_amdgcn_mfma_f32_32x32x16_bf16(a_h[i], b_l[j], acc[i][j], 0, 0, 0);
                }
            __builtin_amdgcn_s_setprio(0);
        }
        // Barrier: (a) prefetch fully landed (vmcnt drain — had compute to
        // hide), (b) all reads of buf[kc] done before it's restaged next iter.
        __syncthreads();
    }

    // Epilogue. C/D layout: col = ln (px), row_local = (r&3) + 8*(r>>2) + 4*h.
    float mvs[4];
#pragma unroll
    for (int j = 0; j < 4; ++j)
        mvs[j] = mask[(size_t)b * HW + pt * TP + wp * 128 + j * 32 + ln] * ESCALE;

    float* rs = (float*)sm;     // [wp 2][row 256][ln 32] = 64 KB (buf area, loop done)
    size_t obase = ((size_t)(b * NS + st * TS)) * HW + pt * TP + wp * 128 + ln;
    _Float16* eb0 = ebuf + obase;
    float*    ob0 = out  + obase;
#pragma unroll
    for (int i = 0; i < 2; ++i) {
        int rb = ws * 64 + i * 32 + 4 * h;
#pragma unroll
        for (int r2 = 0; r2 < 16; ++r2) {
            int row = rb + (r2 & 3) + 8 * (r2 >> 2);
            float tot = 0.0f;
#pragma unroll
            for (int j = 0; j < 4; ++j) {
                float e = __expf(fmaf(acc[i][j][r2], EXP_A, EXP_B)) * mvs[j];
                if (F16) eb0[(size_t)row * HW + j * 32] = (_Float16)e;
                else     ob0[(size_t)row * HW + j * 32] = e;
                tot += e;
            }
            rs[(wp * TS + row) * 32 + ln] = tot;
        }
    }
    __syncthreads();
    int row2 = t & 255, half = t >> 8;
    float tot = 0.0f;
#pragma unroll
    for (int c = 0; c < 32; ++c)
        tot += rs[(half * TS + row2) * 32 + ((c + t) & 31)];  // rotated: no conflict
    atomicAdd(&sums[b * NS + st * TS + row2], tot);
}

// ---------------------------------------------------------------------------
// rescale16: out[b,s,:] = fp16 e[b,s,:] / sums[b,s]. e read is L3-resident.
// ---------------------------------------------------------------------------
__global__ __launch_bounds__(256) void rescale16(
    const float* __restrict__ sums, const _Float16* __restrict__ ebuf,
    float* __restrict__ out)
{
    int bs = blockIdx.x;                       // 0..4095 = b*NS + s
    float inv = 1.0f / sums[bs];
    const h8* p = (const h8*)(ebuf + (size_t)bs * HW);
    float4* o = (float4*)(out + (size_t)bs * HW);
    int t = threadIdx.x;
#pragma unroll
    for (int i = 0; i < 6; ++i) {              // HW/8 = 1536 h8 per row
        int idx = t + i * 256;
        h8 v = p[idx];
        float4 a, c;
        a.x = (float)v[0] * inv; a.y = (float)v[1] * inv;
        a.z = (float)v[2] * inv; a.w = (float)v[3] * inv;
        c.x = (float)v[4] * inv; c.y = (float)v[5] * inv;
        c.z = (float)v[6] * inv; c.w = (float)v[7] * inv;
        o[2 * idx]     = a;
        o[2 * idx + 1] = c;
    }
}

// Fallback: in-place fp32 rescale.
__global__ __launch_bounds__(256) void rescale32(
    const float* __restrict__ sums, float* __restrict__ out)
{
    int bs = blockIdx.x;
    float inv = 1.0f / sums[bs];
    float4* p = (float4*)(out + (size_t)bs * HW);
    int t = threadIdx.x;
#pragma unroll
    for (int i = 0; i < 12; ++i) {
        float4 v = p[t + i * 256];
        v.x *= inv; v.y *= inv; v.z *= inv; v.w *= inv;
        p[t + i * 256] = v;
    }
}

extern "C" void kernel_launch(void* const* d_in, const int* in_sizes, int n_in,
                              void* d_out, int out_size, void* d_ws, size_t ws_size,
                              hipStream_t stream) {
    const float* src  = (const float*)d_in[0];
    const float* tgt  = (const float*)d_in[1];
    const int*   loc  = (const int*)d_in[2];
    const float* mask = (const float*)d_in[3];
    float* out = (float*)d_out;

    char* ws = (char*)d_ws;
    const size_t BPLANE = (size_t)NB * 4 * HW * 32 * sizeof(u16);  // 12.58 MB
    const size_t APLANE = (size_t)NB * 4 * NS * 32 * sizeof(u16);  //  1.05 MB
    const size_t EPLANE = (size_t)NB * NS * HW * sizeof(_Float16); // 100.7 MB
    u16* bhi = (u16*)ws;
    u16* blo = (u16*)(ws + BPLANE);
    u16* ahi = (u16*)(ws + 2 * BPLANE);
    u16* alo = (u16*)(ws + 2 * BPLANE + APLANE);
    float* sums = (float*)(ws + 2 * BPLANE + 2 * APLANE);          // 16 KB used
    _Float16* ebuf = (_Float16*)(ws + 2 * BPLANE + 2 * APLANE + 65536);
    const size_t NEED = 2 * BPLANE + 2 * APLANE + 65536 + EPLANE;  // ~128 MB

    prep<<<dim3((HW / 64) * NB + NB * NS / 2), 256, 0, stream>>>(
        src, tgt, loc, ahi, alo, bhi, blo, sums);

    dim3 g(NPT * NST);   // 768 flat, XCD-chunked decode in-kernel
    if (ws_size >= NEED) {
        corr_fused<1><<<g, 512, 0, stream>>>(bhi, blo, ahi, alo, mask, sums, ebuf, out);
        rescale16<<<dim3(NB * NS), 256, 0, stream>>>(sums, ebuf, out);
    } else {
        corr_fused<0><<<g, 512, 0, stream>>>(bhi, blo, ahi, alo, mask, sums, ebuf, out);
        rescale32<<<dim3(NB * NS), 256, 0, stream>>>(sums, out);
    }
}